// Round 1
// baseline (606.812 us; speedup 1.0000x reference)
//
#include <hip/hip_runtime.h>
#include <hip/hip_bf16.h>
#include <stdint.h>

#define GEPS 1e-20f

typedef __bf16 bf16x8 __attribute__((ext_vector_type(8)));
typedef float  f32x4  __attribute__((ext_vector_type(4)));

typedef const __attribute__((address_space(1))) uint32_t* gptr32;
typedef __attribute__((address_space(3))) uint32_t* lptr32;

__device__ __forceinline__ void load_lds16(const void* g, void* l) {
    __builtin_amdgcn_global_load_lds((gptr32)g, (lptr32)l, 16, 0, 0);
}

__device__ __forceinline__ uint16_t f2bf(float v) {
    __hip_bfloat16 b = __float2bfloat16(v);
    return *(uint16_t*)&b;
}

__device__ __forceinline__ void store_val(uint16_t* C, size_t idx, float v) { C[idx] = f2bf(v); }
__device__ __forceinline__ void store_val(float* C, size_t idx, float v)    { C[idx] = v; }

// ---------------------------------------------------------------------------
// cast fp32 -> bf16, vectorized (n must be multiple of 4)
// ---------------------------------------------------------------------------
__global__ void cast_bf16(const float* __restrict__ in, uint16_t* __restrict__ out, int n) {
    int i = (blockIdx.x * blockDim.x + threadIdx.x) * 4;
    if (i < n) {
        float4 v = *(const float4*)(in + i);
        ushort4 o;
        o.x = f2bf(v.x); o.y = f2bf(v.y); o.z = f2bf(v.z); o.w = f2bf(v.w);
        *(ushort4*)(out + i) = o;
    }
}

// ---------------------------------------------------------------------------
// W (K x N, fp32, row-major) -> Wt (Npad x K, bf16, row-major), zero-pad n>=N
// block 256 threads, 64x64 tile via LDS
// ---------------------------------------------------------------------------
__global__ void transpose_cast(const float* __restrict__ W, uint16_t* __restrict__ Wt,
                               int K, int N, int Npad) {
    __shared__ float tile[64][65];
    const int k0 = blockIdx.y * 64, n0 = blockIdx.x * 64;
    const int tx = threadIdx.x & 63, ty = threadIdx.x >> 6;
    for (int r = ty; r < 64; r += 4) {
        int n = n0 + tx;
        tile[r][tx] = (n < N) ? W[(size_t)(k0 + r) * N + n] : 0.f;
    }
    __syncthreads();
    for (int r = ty; r < 64; r += 4) {
        Wt[(size_t)(n0 + r) * K + k0 + tx] = f2bf(tile[tx][r]);
    }
}

// ---------------------------------------------------------------------------
// C = act(A @ Bt^T + bias)
// A: M x K bf16 row-major.  Bt: Npad x K bf16 row-major (i.e. B transposed).
// 128x128 tile, BK=32, 256 threads = 4 waves (2x2), 16x16x32 bf16 MFMA.
// ACT: 0=none, 1=ELU, 2=sigmoid
// ---------------------------------------------------------------------------
template<int ACT, typename OutT>
__global__ __launch_bounds__(256)
void gemm_bt(const uint16_t* __restrict__ A, const uint16_t* __restrict__ Bt,
             const float* __restrict__ bias, OutT* __restrict__ C,
             int K, int Nout, int ldc) {
    __shared__ __align__(16) uint16_t As[128 * 32];
    __shared__ __align__(16) uint16_t Bs[128 * 32];

    const int t    = threadIdx.x;
    const int wave = t >> 6, lane = t & 63;
    const int m0 = blockIdx.y * 128, n0 = blockIdx.x * 128;
    const int wm = (wave >> 1) * 64, wn = (wave & 1) * 64;
    const int quad = lane >> 4;
    const int qk   = quad * 8;       // k offset within frag
    const int r15  = lane & 15;

    f32x4 acc[4][4] = {};

    const uint16_t* Ag = A  + (size_t)m0 * K;
    const uint16_t* Bg = Bt + (size_t)n0 * K;

    for (int k0 = 0; k0 < K; k0 += 32) {
        __syncthreads();
        #pragma unroll
        for (int rd = 0; rd < 2; ++rd) {
            int c = t + rd * 256;            // 16B-chunk index, 0..511
            int row = c >> 2, kc = (c & 3) * 8;
            load_lds16(Ag + (size_t)row * K + k0 + kc, &As[c * 8]);
            load_lds16(Bg + (size_t)row * K + k0 + kc, &Bs[c * 8]);
        }
        __syncthreads();

        bf16x8 a[4], b[4];
        #pragma unroll
        for (int i = 0; i < 4; ++i)
            a[i] = *(const bf16x8*)&As[(wm + i * 16 + r15) * 32 + qk];
        #pragma unroll
        for (int i = 0; i < 4; ++i)
            b[i] = *(const bf16x8*)&Bs[(wn + i * 16 + r15) * 32 + qk];

        #pragma unroll
        for (int mi = 0; mi < 4; ++mi)
            #pragma unroll
            for (int ni = 0; ni < 4; ++ni)
                acc[mi][ni] = __builtin_amdgcn_mfma_f32_16x16x32_bf16(
                    a[mi], b[ni], acc[mi][ni], 0, 0, 0);
    }

    // epilogue: C/D layout col = lane&15, row = quad*4 + reg  [verified m89]
    #pragma unroll
    for (int ni = 0; ni < 4; ++ni) {
        int col = n0 + wn + ni * 16 + r15;
        if (col < Nout) {
            float bv = bias[col];
            #pragma unroll
            for (int mi = 0; mi < 4; ++mi) {
                #pragma unroll
                for (int r = 0; r < 4; ++r) {
                    int row = m0 + wm + mi * 16 + quad * 4 + r;
                    float v = acc[mi][ni][r] + bv;
                    if (ACT == 1) v = (v > 0.f) ? v : (expf(v) - 1.f);
                    else if (ACT == 2) v = 1.f / (1.f + expf(-v));
                    store_val(C, (size_t)row * ldc + col, v);
                }
            }
        }
    }
}

// ---------------------------------------------------------------------------
// In-place Gumbel-softmax epilogue: out holds logits (B x 929 fp32).
// One wave per row; segments unrolled at compile time.
// ---------------------------------------------------------------------------
__global__ __launch_bounds__(256)
void gumbel_epilogue(float* __restrict__ out, const float* __restrict__ u, int B) {
    constexpr int NSEG = 13;
    constexpr int SEGN[NSEG] = {29, 2, 1, 6, 7, 59, 1, 24, 76, 711, 3, 9, 1};
    __shared__ float buf[4][712];

    const int wave = threadIdx.x >> 6, lane = threadIdx.x & 63;
    const int row = blockIdx.x * 4 + wave;
    if (row >= B) return;

    float* rout = out + (size_t)row * 929;
    const float* ru = u + (size_t)row * 929;
    float* wb = buf[wave];

    int off = 0;
    #pragma unroll
    for (int s = 0; s < NSEG; ++s) {
        const int n = SEGN[s];
        if (n > 1) {
            float lmax = -3.4e38f;
            for (int j = lane; j < n; j += 64) {
                float g = -logf(-logf(ru[off + j] + GEPS) + GEPS);
                float y = (rout[off + j] + g) * 1.25f;   // /TEMP, TEMP=0.8
                wb[j] = y;
                lmax = fmaxf(lmax, y);
            }
            #pragma unroll
            for (int o = 32; o > 0; o >>= 1) lmax = fmaxf(lmax, __shfl_xor(lmax, o, 64));
            float lsum = 0.f;
            for (int j = lane; j < n; j += 64) {
                float e = expf(wb[j] - lmax);
                wb[j] = e;
                lsum += e;
            }
            #pragma unroll
            for (int o = 32; o > 0; o >>= 1) lsum += __shfl_xor(lsum, o, 64);
            float inv = 1.f / lsum;
            for (int j = lane; j < n; j += 64) rout[off + j] = wb[j] * inv;
        }
        // n == 1: pass-through, out already holds the logit
        off += n;
    }
}

// ---------------------------------------------------------------------------
extern "C" void kernel_launch(void* const* d_in, const int* in_sizes, int n_in,
                              void* d_out, int out_size, void* d_ws, size_t ws_size,
                              hipStream_t stream) {
    const float* x  = (const float*)d_in[0];
    const float* W1 = (const float*)d_in[1];
    const float* b1 = (const float*)d_in[2];
    const float* W2 = (const float*)d_in[3];
    const float* b2 = (const float*)d_in[4];
    const float* W3 = (const float*)d_in[5];
    const float* b3 = (const float*)d_in[6];
    const float* u  = (const float*)d_in[7];
    float* out = (float*)d_out;

    const int B = 32768, D = 128, H = 1024, O = 929, OP = 1024;

    char* ws = (char*)d_ws;
    uint16_t* xb  = (uint16_t*)ws; ws += (size_t)B * D * 2;   // 8 MB
    uint16_t* w1t = (uint16_t*)ws; ws += (size_t)H * D * 2;   // 0.25 MB
    uint16_t* w2t = (uint16_t*)ws; ws += (size_t)H * H * 2;   // 2 MB
    uint16_t* w3t = (uint16_t*)ws; ws += (size_t)OP * H * 2;  // 2 MB
    uint16_t* h1  = (uint16_t*)ws; ws += (size_t)B * H * 2;   // 64 MB
    uint16_t* h2  = (uint16_t*)ws; ws += (size_t)B * H * 2;   // 64 MB

    cast_bf16<<<(B * D / 4 + 255) / 256, 256, 0, stream>>>(x, xb, B * D);
    transpose_cast<<<dim3(H / 64, D / 64), 256, 0, stream>>>(W1, w1t, D, H, H);
    transpose_cast<<<dim3(H / 64, H / 64), 256, 0, stream>>>(W2, w2t, H, H, H);
    transpose_cast<<<dim3(OP / 64, H / 64), 256, 0, stream>>>(W3, w3t, H, O, OP);

    // h1 = elu(x @ W1 + b1)
    gemm_bt<1, uint16_t><<<dim3(H / 128, B / 128), 256, 0, stream>>>(xb, w1t, b1, h1, D, H, H);
    // h2 = sigmoid(h1 @ W2 + b2)
    gemm_bt<2, uint16_t><<<dim3(H / 128, B / 128), 256, 0, stream>>>(h1, w2t, b2, h2, H, H, H);
    // logits = h2 @ W3 + b3  -> directly into d_out
    gemm_bt<0, float><<<dim3(OP / 128, B / 128), 256, 0, stream>>>(h2, w3t, b3, out, H, O, O);

    // in-place gumbel softmax over segments
    gumbel_epilogue<<<B / 4, 256, 0, stream>>>(out, u, B);
}

// Round 2
// 560.542 us; speedup vs baseline: 1.0825x; 1.0825x over previous
//
#include <hip/hip_runtime.h>
#include <hip/hip_bf16.h>
#include <stdint.h>

#define GEPS 1e-20f

typedef __bf16 bf16x8 __attribute__((ext_vector_type(8)));
typedef float  f32x4  __attribute__((ext_vector_type(4)));

typedef const __attribute__((address_space(1))) uint32_t* gptr32;
typedef __attribute__((address_space(3))) uint32_t* lptr32;

__device__ __forceinline__ void load_lds16(const void* g, void* l) {
    __builtin_amdgcn_global_load_lds((gptr32)g, (lptr32)l, 16, 0, 0);
}

__device__ __forceinline__ uint16_t f2bf(float v) {
    __hip_bfloat16 b = __float2bfloat16(v);
    return *(uint16_t*)&b;
}
__device__ __forceinline__ float bf2f(uint16_t b) {
    uint32_t u = (uint32_t)b << 16;
    return __builtin_bit_cast(float, u);
}

__device__ __forceinline__ void store_val(uint16_t* C, size_t idx, float v) { C[idx] = f2bf(v); }
__device__ __forceinline__ void store_val(float* C, size_t idx, float v)    { C[idx] = v; }

// ---------------------------------------------------------------------------
// cast fp32 -> bf16, vectorized (n must be multiple of 4)
// ---------------------------------------------------------------------------
__global__ void cast_bf16(const float* __restrict__ in, uint16_t* __restrict__ out, int n) {
    int i = (blockIdx.x * blockDim.x + threadIdx.x) * 4;
    if (i < n) {
        float4 v = *(const float4*)(in + i);
        ushort4 o;
        o.x = f2bf(v.x); o.y = f2bf(v.y); o.z = f2bf(v.z); o.w = f2bf(v.w);
        *(ushort4*)(out + i) = o;
    }
}

// ---------------------------------------------------------------------------
// W (K x N, fp32, row-major) -> Wt (Npad x K, bf16, row-major), zero-pad n>=N
// ---------------------------------------------------------------------------
__global__ void transpose_cast(const float* __restrict__ W, uint16_t* __restrict__ Wt,
                               int K, int N, int Npad) {
    __shared__ float tile[64][65];
    const int k0 = blockIdx.y * 64, n0 = blockIdx.x * 64;
    const int tx = threadIdx.x & 63, ty = threadIdx.x >> 6;
    for (int r = ty; r < 64; r += 4) {
        int n = n0 + tx;
        tile[r][tx] = (n < N) ? W[(size_t)(k0 + r) * N + n] : 0.f;
    }
    __syncthreads();
    for (int r = ty; r < 64; r += 4) {
        Wt[(size_t)(n0 + r) * K + k0 + tx] = f2bf(tile[tx][r]);
    }
}

// ---------------------------------------------------------------------------
// C = act(A @ Bt^T + bias)
// A: M x K bf16 row-major.  Bt: Npad x K bf16 row-major.
// 128x128 tile, BK=32, 256 threads = 4 waves (2x2), 16x16x32 bf16 MFMA.
// ACT: 0=none, 1=ELU, 2=sigmoid.  SNG: also store fp32 singleton cols to sngl.
// XCD-aware remap: each of the 8 XCDs owns a contiguous slice of m-tiles and
// sweeps all n-tiles per m, so the A-tile is fetched once into that XCD's L2.
// ---------------------------------------------------------------------------
template<int ACT, typename OutT, bool SNG>
__global__ __launch_bounds__(256)
void gemm_bt(const uint16_t* __restrict__ A, const uint16_t* __restrict__ Bt,
             const float* __restrict__ bias, OutT* __restrict__ C,
             float* __restrict__ sngl,
             int K, int Nout, int ldc) {
    __shared__ __align__(16) uint16_t As[128 * 32];
    __shared__ __align__(16) uint16_t Bs[128 * 32];

    const int t    = threadIdx.x;
    const int wave = t >> 6, lane = t & 63;

    // ---- XCD-aware block remap (gridDim.y must be divisible by 8) ----
    const int nbx = gridDim.x;
    const int bid = blockIdx.y * nbx + blockIdx.x;
    const int xcd = bid & 7;
    const int s   = bid >> 3;
    const int nidx = s % nbx;
    const int midx = xcd * (gridDim.y >> 3) + s / nbx;

    const int m0 = midx * 128, n0 = nidx * 128;
    const int wm = (wave >> 1) * 64, wn = (wave & 1) * 64;
    const int quad = lane >> 4;
    const int qk   = quad * 8;
    const int r15  = lane & 15;

    f32x4 acc[4][4] = {};

    const uint16_t* Ag = A  + (size_t)m0 * K;
    const uint16_t* Bg = Bt + (size_t)n0 * K;

    for (int k0 = 0; k0 < K; k0 += 32) {
        __syncthreads();
        #pragma unroll
        for (int rd = 0; rd < 2; ++rd) {
            int c = t + rd * 256;            // 16B-chunk index, 0..511
            int row = c >> 2, kc = (c & 3) * 8;
            load_lds16(Ag + (size_t)row * K + k0 + kc, &As[c * 8]);
            load_lds16(Bg + (size_t)row * K + k0 + kc, &Bs[c * 8]);
        }
        __syncthreads();

        bf16x8 a[4], b[4];
        #pragma unroll
        for (int i = 0; i < 4; ++i)
            a[i] = *(const bf16x8*)&As[(wm + i * 16 + r15) * 32 + qk];
        #pragma unroll
        for (int i = 0; i < 4; ++i)
            b[i] = *(const bf16x8*)&Bs[(wn + i * 16 + r15) * 32 + qk];

        #pragma unroll
        for (int mi = 0; mi < 4; ++mi)
            #pragma unroll
            for (int ni = 0; ni < 4; ++ni)
                acc[mi][ni] = __builtin_amdgcn_mfma_f32_16x16x32_bf16(
                    a[mi], b[ni], acc[mi][ni], 0, 0, 0);
    }

    // epilogue: C/D layout col = lane&15, row = quad*4 + reg  [verified m89]
    #pragma unroll
    for (int ni = 0; ni < 4; ++ni) {
        int col = n0 + wn + ni * 16 + r15;
        if (col < Nout) {
            float bv = bias[col];
            bool is_sng = SNG && (col == 31 || col == 104 || col == 928);
            #pragma unroll
            for (int mi = 0; mi < 4; ++mi) {
                #pragma unroll
                for (int r = 0; r < 4; ++r) {
                    int row = m0 + wm + mi * 16 + quad * 4 + r;
                    float v = acc[mi][ni][r] + bv;
                    if (ACT == 1) v = (v > 0.f) ? v : (expf(v) - 1.f);
                    else if (ACT == 2) v = 1.f / (1.f + expf(-v));
                    store_val(C, (size_t)row * ldc + col, v);
                    if constexpr (SNG) {
                        if (is_sng) sngl[(size_t)row * 929 + col] = v;
                    }
                }
            }
        }
    }
}

// ---------------------------------------------------------------------------
// Gumbel-softmax epilogue: reads bf16 logits (B x 929), writes fp32 out.
// Singleton columns (31,104,928) already hold fp32 logits in out — skipped.
// One wave per row; segments unrolled at compile time.
// ---------------------------------------------------------------------------
__global__ __launch_bounds__(256)
void gumbel_epilogue(const uint16_t* __restrict__ lg, float* __restrict__ out,
                     const float* __restrict__ u, int B) {
    constexpr int NSEG = 13;
    constexpr int SEGN[NSEG] = {29, 2, 1, 6, 7, 59, 1, 24, 76, 711, 3, 9, 1};
    __shared__ float buf[4][712];

    const int wave = threadIdx.x >> 6, lane = threadIdx.x & 63;
    const int row = blockIdx.x * 4 + wave;
    if (row >= B) return;

    const uint16_t* rlg = lg + (size_t)row * 929;
    float* rout = out + (size_t)row * 929;
    const float* ru = u + (size_t)row * 929;
    float* wb = buf[wave];

    int off = 0;
    #pragma unroll
    for (int s = 0; s < NSEG; ++s) {
        const int n = SEGN[s];
        if (n > 1) {
            float lmax = -3.4e38f;
            for (int j = lane; j < n; j += 64) {
                float g = -logf(-logf(ru[off + j] + GEPS) + GEPS);
                float y = (bf2f(rlg[off + j]) + g) * 1.25f;   // /TEMP, TEMP=0.8
                wb[j] = y;
                lmax = fmaxf(lmax, y);
            }
            #pragma unroll
            for (int o = 32; o > 0; o >>= 1) lmax = fmaxf(lmax, __shfl_xor(lmax, o, 64));
            float lsum = 0.f;
            for (int j = lane; j < n; j += 64) {
                float e = expf(wb[j] - lmax);
                wb[j] = e;
                lsum += e;
            }
            #pragma unroll
            for (int o = 32; o > 0; o >>= 1) lsum += __shfl_xor(lsum, o, 64);
            float inv = 1.f / lsum;
            for (int j = lane; j < n; j += 64) rout[off + j] = wb[j] * inv;
        }
        off += n;
    }
}

// ---------------------------------------------------------------------------
extern "C" void kernel_launch(void* const* d_in, const int* in_sizes, int n_in,
                              void* d_out, int out_size, void* d_ws, size_t ws_size,
                              hipStream_t stream) {
    const float* x  = (const float*)d_in[0];
    const float* W1 = (const float*)d_in[1];
    const float* b1 = (const float*)d_in[2];
    const float* W2 = (const float*)d_in[3];
    const float* b2 = (const float*)d_in[4];
    const float* W3 = (const float*)d_in[5];
    const float* b3 = (const float*)d_in[6];
    const float* u  = (const float*)d_in[7];
    float* out = (float*)d_out;

    const int B = 32768, D = 128, H = 1024, O = 929, OP = 1024;

    char* ws = (char*)d_ws;
    uint16_t* xb  = (uint16_t*)ws; ws += (size_t)B * D * 2;   // 8 MB
    uint16_t* w1t = (uint16_t*)ws; ws += (size_t)H * D * 2;   // 0.25 MB
    uint16_t* w2t = (uint16_t*)ws; ws += (size_t)H * H * 2;   // 2 MB
    uint16_t* w3t = (uint16_t*)ws; ws += (size_t)OP * H * 2;  // 2 MB
    uint16_t* h1  = (uint16_t*)ws; ws += (size_t)B * H * 2;   // 64 MB
    uint16_t* h2  = (uint16_t*)ws; ws += (size_t)B * H * 2;   // 64 MB
    // logits (bf16, B x 929 = 61 MB) alias the h1 buffer — h1 is dead after GEMM2
    uint16_t* lg  = h1;

    cast_bf16<<<(B * D / 4 + 255) / 256, 256, 0, stream>>>(x, xb, B * D);
    transpose_cast<<<dim3(H / 64, D / 64), 256, 0, stream>>>(W1, w1t, D, H, H);
    transpose_cast<<<dim3(H / 64, H / 64), 256, 0, stream>>>(W2, w2t, H, H, H);
    transpose_cast<<<dim3(OP / 64, H / 64), 256, 0, stream>>>(W3, w3t, H, O, OP);

    // h1 = elu(x @ W1 + b1)
    gemm_bt<1, uint16_t, false><<<dim3(H / 128, B / 128), 256, 0, stream>>>(
        xb, w1t, b1, h1, nullptr, D, H, H);
    // h2 = sigmoid(h1 @ W2 + b2)
    gemm_bt<2, uint16_t, false><<<dim3(H / 128, B / 128), 256, 0, stream>>>(
        h1, w2t, b2, h2, nullptr, H, H, H);
    // logits -> bf16 ws buffer; fp32 singleton cols (31,104,928) -> d_out
    gemm_bt<0, uint16_t, true><<<dim3(OP / 128, B / 128), 256, 0, stream>>>(
        h2, w3t, b3, lg, out, H, O, O);

    // gumbel softmax: bf16 logits -> fp32 out (singletons already final)
    gumbel_epilogue<<<B / 4, 256, 0, stream>>>(lg, out, u, B);
}

// Round 4
// 538.504 us; speedup vs baseline: 1.1268x; 1.0409x over previous
//
#include <hip/hip_runtime.h>
#include <hip/hip_bf16.h>
#include <stdint.h>

#define GEPS 1e-20f

typedef __bf16 bf16x8 __attribute__((ext_vector_type(8)));
typedef float  f32x4  __attribute__((ext_vector_type(4)));

typedef const __attribute__((address_space(1))) uint32_t* gptr32;
typedef __attribute__((address_space(3))) uint32_t* lptr32;

__device__ __forceinline__ void load_lds16(const void* g, void* l) {
    __builtin_amdgcn_global_load_lds((gptr32)g, (lptr32)l, 16, 0, 0);
}

__device__ __forceinline__ uint16_t f2bf(float v) {
    __hip_bfloat16 b = __float2bfloat16(v);
    return *(uint16_t*)&b;
}
__device__ __forceinline__ float bf2f(uint16_t b) {
    uint32_t u = (uint32_t)b << 16;
    return __builtin_bit_cast(float, u);
}

// hardware transcendentals: v_log_f32 = log2(x), v_exp_f32 = 2^x  (~1 ULP)
#define LN2   0.69314718056f
#define LOG2E 1.44269504089f
__device__ __forceinline__ float fast_log(float x) { return __builtin_amdgcn_logf(x) * LN2; }
__device__ __forceinline__ float fast_exp(float x) { return __builtin_amdgcn_exp2f(x * LOG2E); }
__device__ __forceinline__ float fast_exp2(float x) { return __builtin_amdgcn_exp2f(x); }

__device__ __forceinline__ void store_val(uint16_t* C, size_t idx, float v) { C[idx] = f2bf(v); }
__device__ __forceinline__ void store_val(float* C, size_t idx, float v)    { C[idx] = v; }

// ---------------------------------------------------------------------------
// cast fp32 -> bf16, vectorized (n must be multiple of 4)
// ---------------------------------------------------------------------------
__global__ void cast_bf16(const float* __restrict__ in, uint16_t* __restrict__ out, int n) {
    int i = (blockIdx.x * blockDim.x + threadIdx.x) * 4;
    if (i < n) {
        float4 v = *(const float4*)(in + i);
        ushort4 o;
        o.x = f2bf(v.x); o.y = f2bf(v.y); o.z = f2bf(v.z); o.w = f2bf(v.w);
        *(ushort4*)(out + i) = o;
    }
}

// ---------------------------------------------------------------------------
// W (K x N, fp32, row-major) -> Wt (Npad x K, bf16, row-major), zero-pad n>=N
// ---------------------------------------------------------------------------
__global__ void transpose_cast(const float* __restrict__ W, uint16_t* __restrict__ Wt,
                               int K, int N, int Npad) {
    __shared__ float tile[64][65];
    const int k0 = blockIdx.y * 64, n0 = blockIdx.x * 64;
    const int tx = threadIdx.x & 63, ty = threadIdx.x >> 6;
    for (int r = ty; r < 64; r += 4) {
        int n = n0 + tx;
        tile[r][tx] = (n < N) ? W[(size_t)(k0 + r) * N + n] : 0.f;
    }
    __syncthreads();
    for (int r = ty; r < 64; r += 4) {
        Wt[(size_t)(n0 + r) * K + k0 + tx] = f2bf(tile[tx][r]);
    }
}

// ---------------------------------------------------------------------------
// C = act(A @ Bt^T + bias)
// A: M x K bf16 row-major.  Bt: Npad x K bf16 row-major.
// 128x128 tile, BK=32, 256 threads = 4 waves (2x2), 16x16x32 bf16 MFMA.
// ACT: 0=none, 1=ELU, 2=sigmoid.  SNG: also store fp32 singleton cols to sngl.
// XCD-aware remap: each of the 8 XCDs owns a contiguous slice of m-tiles and
// sweeps all n-tiles per m, so the A-tile is fetched once into that XCD's L2.
// ---------------------------------------------------------------------------
template<int ACT, typename OutT, bool SNG>
__global__ __launch_bounds__(256)
void gemm_bt(const uint16_t* __restrict__ A, const uint16_t* __restrict__ Bt,
             const float* __restrict__ bias, OutT* __restrict__ C,
             float* __restrict__ sngl,
             int K, int Nout, int ldc) {
    __shared__ __align__(16) uint16_t As[128 * 32];
    __shared__ __align__(16) uint16_t Bs[128 * 32];

    const int t    = threadIdx.x;
    const int wave = t >> 6, lane = t & 63;

    // ---- XCD-aware block remap (gridDim.y must be divisible by 8) ----
    const int nbx = gridDim.x;
    const int bid = blockIdx.y * nbx + blockIdx.x;
    const int xcd = bid & 7;
    const int s   = bid >> 3;
    const int nidx = s % nbx;
    const int midx = xcd * (gridDim.y >> 3) + s / nbx;

    const int m0 = midx * 128, n0 = nidx * 128;
    const int wm = (wave >> 1) * 64, wn = (wave & 1) * 64;
    const int quad = lane >> 4;
    const int qk   = quad * 8;
    const int r15  = lane & 15;

    f32x4 acc[4][4] = {};

    const uint16_t* Ag = A  + (size_t)m0 * K;
    const uint16_t* Bg = Bt + (size_t)n0 * K;

    for (int k0 = 0; k0 < K; k0 += 32) {
        __syncthreads();
        #pragma unroll
        for (int rd = 0; rd < 2; ++rd) {
            int c = t + rd * 256;            // 16B-chunk index, 0..511
            int row = c >> 2, kc = (c & 3) * 8;
            load_lds16(Ag + (size_t)row * K + k0 + kc, &As[c * 8]);
            load_lds16(Bg + (size_t)row * K + k0 + kc, &Bs[c * 8]);
        }
        __syncthreads();

        bf16x8 a[4], b[4];
        #pragma unroll
        for (int i = 0; i < 4; ++i)
            a[i] = *(const bf16x8*)&As[(wm + i * 16 + r15) * 32 + qk];
        #pragma unroll
        for (int i = 0; i < 4; ++i)
            b[i] = *(const bf16x8*)&Bs[(wn + i * 16 + r15) * 32 + qk];

        #pragma unroll
        for (int mi = 0; mi < 4; ++mi)
            #pragma unroll
            for (int ni = 0; ni < 4; ++ni)
                acc[mi][ni] = __builtin_amdgcn_mfma_f32_16x16x32_bf16(
                    a[mi], b[ni], acc[mi][ni], 0, 0, 0);
    }

    // epilogue: C/D layout col = lane&15, row = quad*4 + reg  [verified m89]
    #pragma unroll
    for (int ni = 0; ni < 4; ++ni) {
        int col = n0 + wn + ni * 16 + r15;
        if (col < Nout) {
            float bv = bias[col];
            bool is_sng = SNG && (col == 31 || col == 104 || col == 928);
            #pragma unroll
            for (int mi = 0; mi < 4; ++mi) {
                #pragma unroll
                for (int r = 0; r < 4; ++r) {
                    int row = m0 + wm + mi * 16 + quad * 4 + r;
                    float v = acc[mi][ni][r] + bv;
                    if (ACT == 1) v = (v > 0.f) ? v : (fast_exp(v) - 1.f);
                    else if (ACT == 2) v = 1.f / (1.f + fast_exp(-v));
                    store_val(C, (size_t)row * ldc + col, v);
                    if constexpr (SNG) {
                        if (is_sng) sngl[(size_t)row * 929 + col] = v;
                    }
                }
            }
        }
    }
}

// ---------------------------------------------------------------------------
// Gumbel-softmax epilogue: reads bf16 logits (B x 929), writes fp32 out.
// Singleton columns (31,104,928) already hold fp32 logits in out — skipped.
// One wave per row; segments unrolled at compile time. HW transcendentals.
// ---------------------------------------------------------------------------
__global__ __launch_bounds__(256)
void gumbel_epilogue(const uint16_t* __restrict__ lg, float* __restrict__ out,
                     const float* __restrict__ u, int B) {
    constexpr int NSEG = 13;
    constexpr int SEGN[NSEG] = {29, 2, 1, 6, 7, 59, 1, 24, 76, 711, 3, 9, 1};
    __shared__ float buf[4][712];

    const int wave = threadIdx.x >> 6, lane = threadIdx.x & 63;
    const int row = blockIdx.x * 4 + wave;
    if (row >= B) return;

    const uint16_t* rlg = lg + (size_t)row * 929;
    float* rout = out + (size_t)row * 929;
    const float* ru = u + (size_t)row * 929;
    float* wb = buf[wave];

    int off = 0;
    #pragma unroll
    for (int s = 0; s < NSEG; ++s) {
        const int n = SEGN[s];
        if (n > 1) {
            float lmax = -3.4e38f;
            for (int j = lane; j < n; j += 64) {
                float g = -fast_log(-fast_log(ru[off + j] + GEPS) + GEPS);
                float y = (bf2f(rlg[off + j]) + g) * 1.25f;   // /TEMP, TEMP=0.8
                wb[j] = y;
                lmax = fmaxf(lmax, y);
            }
            #pragma unroll
            for (int o = 32; o > 0; o >>= 1) lmax = fmaxf(lmax, __shfl_xor(lmax, o, 64));
            float lsum = 0.f;
            for (int j = lane; j < n; j += 64) {
                // e = 2^((y - lmax) * log2e)
                float e = fast_exp2((wb[j] - lmax) * LOG2E);
                wb[j] = e;
                lsum += e;
            }
            #pragma unroll
            for (int o = 32; o > 0; o >>= 1) lsum += __shfl_xor(lsum, o, 64);
            float inv = 1.f / lsum;
            for (int j = lane; j < n; j += 64) rout[off + j] = wb[j] * inv;
        }
        off += n;
    }
}

// ---------------------------------------------------------------------------
extern "C" void kernel_launch(void* const* d_in, const int* in_sizes, int n_in,
                              void* d_out, int out_size, void* d_ws, size_t ws_size,
                              hipStream_t stream) {
    const float* x  = (const float*)d_in[0];
    const float* W1 = (const float*)d_in[1];
    const float* b1 = (const float*)d_in[2];
    const float* W2 = (const float*)d_in[3];
    const float* b2 = (const float*)d_in[4];
    const float* W3 = (const float*)d_in[5];
    const float* b3 = (const float*)d_in[6];
    const float* u  = (const float*)d_in[7];
    float* out = (float*)d_out;

    const int B = 32768, D = 128, H = 1024, O = 929, OP = 1024;

    char* ws = (char*)d_ws;
    uint16_t* xb  = (uint16_t*)ws; ws += (size_t)B * D * 2;   // 8 MB
    uint16_t* w1t = (uint16_t*)ws; ws += (size_t)H * D * 2;   // 0.25 MB
    uint16_t* w2t = (uint16_t*)ws; ws += (size_t)H * H * 2;   // 2 MB
    uint16_t* w3t = (uint16_t*)ws; ws += (size_t)OP * H * 2;  // 2 MB
    uint16_t* h1  = (uint16_t*)ws; ws += (size_t)B * H * 2;   // 64 MB
    uint16_t* h2  = (uint16_t*)ws; ws += (size_t)B * H * 2;   // 64 MB
    // logits (bf16, B x 929 = 61 MB) alias the h1 buffer — h1 is dead after GEMM2
    uint16_t* lg  = h1;

    cast_bf16<<<(B * D / 4 + 255) / 256, 256, 0, stream>>>(x, xb, B * D);
    transpose_cast<<<dim3(H / 64, D / 64), 256, 0, stream>>>(W1, w1t, D, H, H);
    transpose_cast<<<dim3(H / 64, H / 64), 256, 0, stream>>>(W2, w2t, H, H, H);
    transpose_cast<<<dim3(OP / 64, H / 64), 256, 0, stream>>>(W3, w3t, H, O, OP);

    // h1 = elu(x @ W1 + b1)
    gemm_bt<1, uint16_t, false><<<dim3(H / 128, B / 128), 256, 0, stream>>>(
        xb, w1t, b1, h1, nullptr, D, H, H);
    // h2 = sigmoid(h1 @ W2 + b2)
    gemm_bt<2, uint16_t, false><<<dim3(H / 128, B / 128), 256, 0, stream>>>(
        h1, w2t, b2, h2, nullptr, H, H, H);
    // logits -> bf16 ws buffer; fp32 singleton cols (31,104,928) -> d_out
    gemm_bt<0, uint16_t, true><<<dim3(OP / 128, B / 128), 256, 0, stream>>>(
        h2, w3t, b3, lg, out, H, O, O);

    // gumbel softmax: bf16 logits -> fp32 out (singletons already final)
    gumbel_epilogue<<<B / 4, 256, 0, stream>>>(lg, out, u, B);
}